// Round 3
// baseline (256.541 us; speedup 1.0000x reference)
//
#include <hip/hip_runtime.h>
#include <math.h>

// One thread per query point.
// grid: [64][64][32][32][16] fp32 (256 MB, ~L3-resident)
// per point: 16 corner gathers (float4 x4 each), blend (with the reference's
// swapped-corner quirk), MLP 16->64->3, sigmoid*255
__global__ __launch_bounds__(256) void gridnet_kernel(
    const float* __restrict__ x,
    const float* __restrict__ grid,
    const float* __restrict__ w1,   // [16][64]
    const float* __restrict__ b1,   // [64]
    const float* __restrict__ w2,   // [64][3]
    const float* __restrict__ b2,   // [3]
    float* __restrict__ out,        // [N][3]
    int N)
{
    __shared__ float w1s[16 * 64];
    __shared__ float b1s[64];
    __shared__ float w2s[64 * 3];
    __shared__ float b2s[4];

    const int t = threadIdx.x;
    for (int i = t; i < 1024; i += 256) w1s[i] = w1[i];
    if (t < 64)  b1s[t] = b1[t];
    if (t < 192) w2s[t] = w2[t];
    if (t < 3)   b2s[t] = b2[t];
    __syncthreads();

    const int gid = blockIdx.x * 256 + t;
    if (gid >= N) return;

    const float4 xv = reinterpret_cast<const float4*>(x)[gid];

    // Coordinate -> grid index space. Must be BIT-EXACT vs the reference's
    // f32 op sequence: (x - lo) / span * count, with lo/span produced by
    // float64 python-scalar arithmetic then cast to f32. Do NOT fold the
    // divide into a reciprocal multiply (changes trunc decisions at cell
    // boundaries -> discrete 8-ish output errors at a handful of points).
    const float lo1 = (float)(-M_PI);
    const float sp0 = (float)(M_PI);
    const float sp1 = (float)(2.0 * M_PI);
    const float lo2 = (float)(0.5 * M_PI);
    const float sp2 = (float)(0.85 * M_PI - 0.5 * M_PI);
    const float lo3 = (float)(-0.85 * M_PI);
    const float sp3 = (float)(-0.5 * M_PI - (-0.85 * M_PI));

    const float c0 = (xv.x - 0.0f) / sp0 * 63.0f;
    const float c1 = (xv.y - lo1) / sp1 * 63.0f;
    const float c2 = (xv.z - lo2) / sp2 * 31.0f;
    const float c3 = (xv.w - lo3) / sp3 * 31.0f;

    const int tlx = (int)c0;   // non-negative -> trunc == floor == jnp.mod base
    const int tly = (int)c1;
    const int tlz = (int)c2;
    const int tlw = (int)c3;

    const float xf = c0 - (float)tlx;
    const float yf = c1 - (float)tly;
    const float zf = c2 - (float)tlz;
    const float wf = c3 - (float)tlw;

    const int brx = min(tlx + 1, 63);
    const int bry = min(tly + 1, 63);
    const int brz = min(tlz + 1, 31);
    const int brw = min(tlw + 1, 31);

    const float wx0 = 1.0f - xf, wx1 = xf;
    const float wy0 = 1.0f - yf, wy1 = yf;
    const float wz0 = 1.0f - zf, wz1 = zf;
    const float ww0 = 1.0f - wf, ww1 = wf;

    // Per-corner (y,z,w) weight table. NOTE: the reference's blend tree is
    // NOT standard quadlinear — corners (y1,z0,w1) and (y1,z1,w0) have
    // swapped (z,w) weights. Faithfully reproduced.
    float cw[2][2][2];
    cw[0][0][0] = wy0 * wz0 * ww0;
    cw[0][0][1] = wy0 * wz0 * ww1;
    cw[0][1][0] = wy0 * wz1 * ww0;
    cw[0][1][1] = wy0 * wz1 * ww1;
    cw[1][0][0] = wy1 * wz0 * ww0;
    cw[1][0][1] = wy1 * wz1 * ww0;   // swapped (reference quirk)
    cw[1][1][0] = wy1 * wz0 * ww1;   // swapped (reference quirk)
    cw[1][1][1] = wy1 * wz1 * ww1;

    const float wxv[2] = {wx0, wx1};
    const int axv[2] = {tlx, brx};
    const int ayv[2] = {tly, bry};
    const int azv[2] = {tlz, brz};
    const int awv[2] = {tlw, brw};

    float feat[16];
    #pragma unroll
    for (int f = 0; f < 16; ++f) feat[f] = 0.0f;

    #pragma unroll
    for (int iy = 0; iy < 2; ++iy) {
        #pragma unroll
        for (int ix = 0; ix < 2; ++ix) {
            const int base1 = (ayv[iy] * 64 + axv[ix]) * 32;
            const float wyx = wxv[ix];
            #pragma unroll
            for (int iz = 0; iz < 2; ++iz) {
                const int base0 = (base1 + azv[iz]) * 32;
                #pragma unroll
                for (int iw = 0; iw < 2; ++iw) {
                    const float w = wyx * cw[iy][iz][iw];
                    const float4* p = reinterpret_cast<const float4*>(
                        grid + (size_t)(base0 + awv[iw]) * 16);
                    const float4 v0 = p[0];
                    const float4 v1 = p[1];
                    const float4 v2 = p[2];
                    const float4 v3 = p[3];
                    feat[0]  += w * v0.x;  feat[1]  += w * v0.y;
                    feat[2]  += w * v0.z;  feat[3]  += w * v0.w;
                    feat[4]  += w * v1.x;  feat[5]  += w * v1.y;
                    feat[6]  += w * v1.z;  feat[7]  += w * v1.w;
                    feat[8]  += w * v2.x;  feat[9]  += w * v2.y;
                    feat[10] += w * v2.z;  feat[11] += w * v2.w;
                    feat[12] += w * v3.x;  feat[13] += w * v3.y;
                    feat[14] += w * v3.z;  feat[15] += w * v3.w;
                }
            }
        }
    }

    // MLP: h = leaky_relu(feat @ w1 + b1); out = sigmoid(h @ w2 + b2) * 255
    float o0 = b2s[0];
    float o1 = b2s[1];
    float o2 = b2s[2];

    #pragma unroll
    for (int j4 = 0; j4 < 16; ++j4) {
        float4 h = reinterpret_cast<const float4*>(b1s)[j4];
        #pragma unroll
        for (int i = 0; i < 16; ++i) {
            const float4 wv = reinterpret_cast<const float4*>(w1s)[i * 16 + j4];
            h.x += feat[i] * wv.x;
            h.y += feat[i] * wv.y;
            h.z += feat[i] * wv.z;
            h.w += feat[i] * wv.w;
        }
        const float hx = (h.x >= 0.0f) ? h.x : 0.01f * h.x;
        const float hy = (h.y >= 0.0f) ? h.y : 0.01f * h.y;
        const float hz = (h.z >= 0.0f) ? h.z : 0.01f * h.z;
        const float hw = (h.w >= 0.0f) ? h.w : 0.01f * h.w;
        const float* w2p = w2s + j4 * 12;
        o0 += hx * w2p[0] + hy * w2p[3] + hz * w2p[6] + hw * w2p[9];
        o1 += hx * w2p[1] + hy * w2p[4] + hz * w2p[7] + hw * w2p[10];
        o2 += hx * w2p[2] + hy * w2p[5] + hz * w2p[8] + hw * w2p[11];
    }

    const float r0 = 255.0f / (1.0f + expf(-o0));
    const float r1 = 255.0f / (1.0f + expf(-o1));
    const float r2 = 255.0f / (1.0f + expf(-o2));

    float* op = out + (size_t)gid * 3;
    op[0] = r0;
    op[1] = r1;
    op[2] = r2;
}

extern "C" void kernel_launch(void* const* d_in, const int* in_sizes, int n_in,
                              void* d_out, int out_size, void* d_ws, size_t ws_size,
                              hipStream_t stream) {
    const float* x    = (const float*)d_in[0];
    const float* grid = (const float*)d_in[1];
    const float* w1   = (const float*)d_in[2];
    const float* b1   = (const float*)d_in[3];
    const float* w2   = (const float*)d_in[4];
    const float* b2   = (const float*)d_in[5];
    float* out = (float*)d_out;

    const int N = in_sizes[0] / 4;  // x is [N,4]
    const int blocks = (N + 255) / 256;
    gridnet_kernel<<<blocks, 256, 0, stream>>>(x, grid, w1, b1, w2, b2, out, N);
}